// Round 1
// baseline (738.332 us; speedup 1.0000x reference)
//
#include <hip/hip_runtime.h>

// ---------------------------------------------------------------------------
// IDynamicDWConv pipeline, fp32 end-to-end.
//   x[2,64,256,256] -> avgpool4 -> 3x resblock(conv3x3 C64) @64x64
//   -> maxpool2 -> 3x resblock @32x32 -> conv1x1 64->576 = wt[2,576,32,32]
//   -> (bilinear x8 upsample fused into) dynamic depthwise 3x3 over x.
// ---------------------------------------------------------------------------

__global__ __launch_bounds__(256) void avgpool4_k(const float* __restrict__ x,
                                                  float* __restrict__ y) {
    int idx = blockIdx.x * 256 + threadIdx.x;      // 2*64*64*64 = 524288
    int wo = idx & 63;
    int ho = (idx >> 6) & 63;
    int cz = idx >> 12;                            // n*64+c, 0..127
    const float* base = x + ((long)cz * 256 + ho * 4) * 256 + wo * 4;
    float s = 0.f;
#pragma unroll
    for (int r = 0; r < 4; ++r) {
        float4 v = *(const float4*)(base + r * 256);
        s += v.x + v.y + v.z + v.w;
    }
    y[idx] = s * 0.0625f;
}

__global__ __launch_bounds__(256) void maxpool2_k(const float* __restrict__ x,
                                                  float* __restrict__ y) {
    int idx = blockIdx.x * 256 + threadIdx.x;      // 2*64*32*32 = 131072
    int wo = idx & 31;
    int ho = (idx >> 5) & 31;
    int cz = idx >> 10;                            // n*64+c
    const float* base = x + ((long)cz * 64 + ho * 2) * 64 + wo * 2;
    float a = base[0], b = base[1], c = base[64], d = base[65];
    y[idx] = fmaxf(fmaxf(a, b), fmaxf(c, d));
}

// Direct 3x3 SAME conv, C_in=C_out=64. Block: 256 thr = 16x16 spatial tile,
// 4 output channels per block. Input staged in LDS in 32-channel chunks.
// Weight indices are block-uniform -> scalar loads through K$.
__global__ __launch_bounds__(256) void conv3x3_k(
    const float* __restrict__ in, const float* __restrict__ wgt,
    const float* __restrict__ bias, const float* __restrict__ res,
    float* __restrict__ out, int S, int lrelu) {
    __shared__ float s_in[32 * 324];               // 32 ch x 18x18, 41472 B
    const int tid = threadIdx.x;
    const int lx = tid & 15, ly = tid >> 4;
    const int tw = blockIdx.x * 16, th = blockIdx.y * 16;
    const int n = blockIdx.z >> 4, cog = blockIdx.z & 15;
    const int oc0 = cog * 4;

    float acc[4] = {0.f, 0.f, 0.f, 0.f};

    for (int chunk = 0; chunk < 64; chunk += 32) {
        if (chunk) __syncthreads();
        for (int idx = tid; idx < 32 * 324; idx += 256) {
            int c = idx / 324;
            int rem = idx - c * 324;
            int r = rem / 18;
            int col = rem - r * 18;
            int gh = th + r - 1, gw = tw + col - 1;
            float v = 0.f;
            if ((unsigned)gh < (unsigned)S && (unsigned)gw < (unsigned)S)
                v = in[((long)(n * 64 + chunk + c) * S + gh) * S + gw];
            s_in[idx] = v;
        }
        __syncthreads();
#pragma unroll 4
        for (int ci = 0; ci < 32; ++ci) {
            const float* sp = &s_in[ci * 324 + ly * 18 + lx];
            float xv[9];
#pragma unroll
            for (int r = 0; r < 3; ++r)
#pragma unroll
                for (int c2 = 0; c2 < 3; ++c2)
                    xv[r * 3 + c2] = sp[r * 18 + c2];
            const float* wp = wgt + ((long)oc0 * 64 + (chunk + ci)) * 9;
#pragma unroll
            for (int oc = 0; oc < 4; ++oc) {
#pragma unroll
                for (int t = 0; t < 9; ++t)
                    acc[oc] += xv[t] * wp[oc * 576 + t];
            }
        }
    }

    const int h = th + ly, w = tw + lx;
#pragma unroll
    for (int oc = 0; oc < 4; ++oc) {
        float v = acc[oc] + bias[oc0 + oc];
        if (lrelu) v = v > 0.f ? v : 0.1f * v;
        long off = ((long)(n * 64 + oc0 + oc) * S + h) * S + w;
        if (res) v += res[off];
        out[off] = v;
    }
}

// 1x1 conv 64 -> 576 at 32x32. Block: 256 px tile, 8 out-channels.
__global__ __launch_bounds__(256) void conv1x1_k(
    const float* __restrict__ in, const float* __restrict__ w,
    const float* __restrict__ b, float* __restrict__ out) {
    __shared__ float s[32 * 256];                  // 32 KB
    const int tid = threadIdx.x;
    const int p0 = blockIdx.x * 256;               // 4 tiles of 1024 px
    const int cog = blockIdx.y;                    // 72 groups of 8
    const int n = blockIdx.z;
    float acc[8];
#pragma unroll
    for (int i = 0; i < 8; ++i) acc[i] = b[cog * 8 + i];
    for (int chunk = 0; chunk < 64; chunk += 32) {
        if (chunk) __syncthreads();
#pragma unroll
        for (int i = 0; i < 32; ++i)
            s[i * 256 + tid] = in[(long)(n * 64 + chunk + i) * 1024 + p0 + tid];
        __syncthreads();
        for (int ci = 0; ci < 32; ++ci) {
            float v = s[ci * 256 + tid];
#pragma unroll
            for (int oc = 0; oc < 8; ++oc)
                acc[oc] += v * w[(long)(cog * 8 + oc) * 64 + chunk + ci];
        }
    }
#pragma unroll
    for (int oc = 0; oc < 8; ++oc)
        out[(long)(n * 576 + cog * 8 + oc) * 1024 + p0 + tid] = acc[oc];
}

// Fused bilinear x8 upsample (half-pixel, edge clamp) + dynamic depthwise 3x3
// with replicate padding on x. One thread per output pixel.
__global__ __launch_bounds__(256) void dynconv_k(
    const float* __restrict__ x, const float* __restrict__ wt,
    float* __restrict__ out) {
    const int w = threadIdx.x;                     // 0..255
    const int h = blockIdx.x;                      // 0..255
    const int cz = blockIdx.y;                     // n*64+c, 0..127

    float src_h = h * 0.125f - 0.4375f;
    int h0 = (int)floorf(src_h);
    float fh = src_h - (float)h0;
    int h0c = min(max(h0, 0), 31), h1c = min(max(h0 + 1, 0), 31);
    float src_w = w * 0.125f - 0.4375f;
    int w0 = (int)floorf(src_w);
    float fw = src_w - (float)w0;
    int w0c = min(max(w0, 0), 31), w1c = min(max(w0 + 1, 0), 31);

    // wt channel base: n*576 + c*9 == (n*64+c)*9
    const float* wtb = wt + (long)cz * 9 * 1024;
    const float* xb = x + (long)cz * 65536;
    float acc = 0.f;
#pragma unroll
    for (int tap = 0; tap < 9; ++tap) {
        const float* p = wtb + tap * 1024;
        float w00 = p[h0c * 32 + w0c], w01 = p[h0c * 32 + w1c];
        float w10 = p[h1c * 32 + w0c], w11 = p[h1c * 32 + w1c];
        float top = w00 + fw * (w01 - w00);
        float bot = w10 + fw * (w11 - w10);
        float wv = top + fh * (bot - top);
        int dh = tap / 3, dw = tap - dh * 3;
        int hh = min(max(h + dh - 1, 0), 255);
        int ww = min(max(w + dw - 1, 0), 255);
        acc += xb[hh * 256 + ww] * wv;
    }
    out[(long)cz * 65536 + h * 256 + w] = acc;
}

extern "C" void kernel_launch(void* const* d_in, const int* in_sizes, int n_in,
                              void* d_out, int out_size, void* d_ws, size_t ws_size,
                              hipStream_t stream) {
    const float* x    = (const float*)d_in[0];
    const float* b1w1 = (const float*)d_in[1];
    const float* b1b1 = (const float*)d_in[2];
    const float* b1w2 = (const float*)d_in[3];
    const float* b1b2 = (const float*)d_in[4];
    const float* b2w1 = (const float*)d_in[5];
    const float* b2b1 = (const float*)d_in[6];
    const float* b2w2 = (const float*)d_in[7];
    const float* b2b2 = (const float*)d_in[8];
    const float* tokw = (const float*)d_in[9];
    const float* tokb = (const float*)d_in[10];
    float* out = (float*)d_out;
    float* ws = (float*)d_ws;

    // Stage 1 buffers: [2,64,64,64] = 524288 floats each.
    float* A = ws;
    float* B = ws + 524288;
    float* T = ws + 1048576;
    // Stage 2 buffers overlay A (dead after maxpool reads B):
    float* P = ws;                  // [2,64,32,32] = 131072
    float* Q = ws + 131072;
    float* U = ws + 262144;
    float* WT = ws + 393216;        // [2,576,32,32] = 1179648 -> ends at 1572864 (6 MB)

    const int WSZ = 64 * 64 * 9;    // per-resblock weight stride

    avgpool4_k<<<2048, 256, 0, stream>>>(x, A);

    dim3 g64(4, 4, 32);
    conv3x3_k<<<g64, 256, 0, stream>>>(A, b1w1 + 0 * WSZ, b1b1 + 0,   nullptr, T, 64, 1);
    conv3x3_k<<<g64, 256, 0, stream>>>(T, b1w2 + 0 * WSZ, b1b2 + 0,   A,       B, 64, 0);
    conv3x3_k<<<g64, 256, 0, stream>>>(B, b1w1 + 1 * WSZ, b1b1 + 64,  nullptr, T, 64, 1);
    conv3x3_k<<<g64, 256, 0, stream>>>(T, b1w2 + 1 * WSZ, b1b2 + 64,  B,       A, 64, 0);
    conv3x3_k<<<g64, 256, 0, stream>>>(A, b1w1 + 2 * WSZ, b1b1 + 128, nullptr, T, 64, 1);
    conv3x3_k<<<g64, 256, 0, stream>>>(T, b1w2 + 2 * WSZ, b1b2 + 128, A,       B, 64, 0);

    maxpool2_k<<<512, 256, 0, stream>>>(B, P);

    dim3 g32(2, 2, 32);
    conv3x3_k<<<g32, 256, 0, stream>>>(P, b2w1 + 0 * WSZ, b2b1 + 0,   nullptr, U, 32, 1);
    conv3x3_k<<<g32, 256, 0, stream>>>(U, b2w2 + 0 * WSZ, b2b2 + 0,   P,       Q, 32, 0);
    conv3x3_k<<<g32, 256, 0, stream>>>(Q, b2w1 + 1 * WSZ, b2b1 + 64,  nullptr, U, 32, 1);
    conv3x3_k<<<g32, 256, 0, stream>>>(U, b2w2 + 1 * WSZ, b2b2 + 64,  Q,       P, 32, 0);
    conv3x3_k<<<g32, 256, 0, stream>>>(P, b2w1 + 2 * WSZ, b2b1 + 128, nullptr, U, 32, 1);
    conv3x3_k<<<g32, 256, 0, stream>>>(U, b2w2 + 2 * WSZ, b2b2 + 128, P,       Q, 32, 0);

    conv1x1_k<<<dim3(4, 72, 2), 256, 0, stream>>>(Q, tokw, tokb, WT);

    dynconv_k<<<dim3(256, 128), 256, 0, stream>>>(x, WT, out);
}